// Round 8
// baseline (224.619 us; speedup 1.0000x reference)
//
#include <hip/hip_runtime.h>
#include <hip/hip_bf16.h>

// NT-Xent loss, MI355X. B=4096, C=512, N=8192, tau=0.1.
// ws layout: [0, 8MB)            bf16 normalized Z (ushort[8192*512])
//            [8MB, 8MB+32KB)     float rowsum[8192]
//            [8MB+32KB, +16KB)   float pos10[4096]  (pos_dot/tau, exact fp32)
//            [8MB+48KB, +4B)     uint ticket

#define BDIM 4096
#define CDIM 512
#define NROWS 8192
#define NTILE 64    // 8192 / 128
#define NBLK 544    // sum over rows of ceil((64-by)/4) chunks; 544 = 8*68

typedef __attribute__((ext_vector_type(4))) float f32x4;
typedef __attribute__((ext_vector_type(8))) short bf16x8;

#define AS1 __attribute__((address_space(1)))
#define AS3 __attribute__((address_space(3)))

__device__ __forceinline__ unsigned short f2bf_rne(float x) {
    unsigned u = __float_as_uint(x);
    u += 0x7fffu + ((u >> 16) & 1u);
    return (unsigned short)(u >> 16);
}

// ------- kernel 1: L2-normalize -> bf16, exact positive dot, zero rowsum/out/ticket -------
__global__ __launch_bounds__(256) void normalize_kernel(
    const float* __restrict__ z1, const float* __restrict__ z2,
    unsigned short* __restrict__ zb, float* __restrict__ pos10,
    float* __restrict__ rowsum, float* __restrict__ out,
    unsigned* __restrict__ ticket) {
    if (blockIdx.x == 0) {  // fused zero-init (stream order -> visible to kernel 2)
#pragma unroll
        for (int i = 0; i < NROWS / 256; ++i) rowsum[i * 256 + threadIdx.x] = 0.f;
        if (threadIdx.x == 0) { out[0] = 0.f; ticket[0] = 0u; }
    }
    const int w = threadIdx.x >> 6, lane = threadIdx.x & 63;
    const int r = blockIdx.x * 4 + w;  // pair index 0..4095
    const float4* p1 = (const float4*)(z1 + (size_t)r * CDIM);
    const float4* p2 = (const float4*)(z2 + (size_t)r * CDIM);
    float4 a0 = p1[lane], a1 = p1[64 + lane];
    float4 b0 = p2[lane], b1 = p2[64 + lane];
    float s1 = a0.x * a0.x + a0.y * a0.y + a0.z * a0.z + a0.w * a0.w +
               a1.x * a1.x + a1.y * a1.y + a1.z * a1.z + a1.w * a1.w;
    float s2 = b0.x * b0.x + b0.y * b0.y + b0.z * b0.z + b0.w * b0.w +
               b1.x * b1.x + b1.y * b1.y + b1.z * b1.z + b1.w * b1.w;
    float d = a0.x * b0.x + a0.y * b0.y + a0.z * b0.z + a0.w * b0.w +
              a1.x * b1.x + a1.y * b1.y + a1.z * b1.z + a1.w * b1.w;
#pragma unroll
    for (int m = 1; m < 64; m <<= 1) {
        s1 += __shfl_xor(s1, m, 64);
        s2 += __shfl_xor(s2, m, 64);
        d += __shfl_xor(d, m, 64);
    }
    const float n1 = fmaxf(sqrtf(s1), 1e-12f);
    const float n2 = fmaxf(sqrtf(s2), 1e-12f);
    const float i1 = 1.0f / n1, i2 = 1.0f / n2;
    ushort4 o;
    ushort4* q1 = (ushort4*)(zb + (size_t)r * CDIM);
    ushort4* q2 = (ushort4*)(zb + (size_t)(r + BDIM) * CDIM);
    o.x = f2bf_rne(a0.x * i1); o.y = f2bf_rne(a0.y * i1);
    o.z = f2bf_rne(a0.z * i1); o.w = f2bf_rne(a0.w * i1);
    q1[lane] = o;
    o.x = f2bf_rne(a1.x * i1); o.y = f2bf_rne(a1.y * i1);
    o.z = f2bf_rne(a1.z * i1); o.w = f2bf_rne(a1.w * i1);
    q1[64 + lane] = o;
    o.x = f2bf_rne(b0.x * i2); o.y = f2bf_rne(b0.y * i2);
    o.z = f2bf_rne(b0.z * i2); o.w = f2bf_rne(b0.w * i2);
    q2[lane] = o;
    o.x = f2bf_rne(b1.x * i2); o.y = f2bf_rne(b1.y * i2);
    o.z = f2bf_rne(b1.z * i2); o.w = f2bf_rne(b1.w * i2);
    q2[64 + lane] = o;
    if (lane == 0) pos10[r] = (d / (n1 * n2)) * 10.0f;
}

// ------- kernel 2: triangular fused exp(Z Z^T / tau) row+col sums, chunk-sweep -------
// 128x128 tiles, BK=64, 4 waves 2x2, 64KB dbuf LDS -> 2 blocks/CU.
// Each block owns one (by, chunk-of-<=4 bx tiles) sharing the A panel: one
// prologue per 8..32 K-iters; dbuf pipeline runs through tile boundaries
// (j&1 parity == k&1 since 8 iters/tile). Proven r4 sync structure
// (__syncthreads drains vmcnt+lgkm). LDS XOR-swizzle both-sides (rule #21).
// XCD-chunked bijective blockIdx remap (544 = 8*68). Last block (ticket)
// computes the final loss (rowsum read back via atomicAdd(p,0) for coherence).
__global__ __launch_bounds__(256) void simgemm_kernel(
    const unsigned short* __restrict__ Z, float* __restrict__ rowsum,
    const float* __restrict__ pos10, float* __restrict__ out,
    unsigned* __restrict__ ticket) {
    // XCD-chunk remap, then decode chunk -> (by, bx0, NT)
    const int orig = blockIdx.x;
    int b = (orig & 7) * (NBLK / 8) + (orig >> 3);
    int by = 0;
    while (true) {
        const int ch = (NTILE - by + 3) >> 2;
        if (b < ch) break;
        b -= ch; ++by;
    }
    const int bx0 = by + (b << 2);
    const int NT = min(4, NTILE - bx0);

    __shared__ unsigned short lds[2][2][128 * 64];  // [buf][A/B] = 64 KB
    __shared__ float redsm[4];
    __shared__ unsigned lastsm;

    const int t = threadIdx.x;
    const int lane = t & 63, w = t >> 6;
    const int wr = w >> 1, wc = w & 1;

    f32x4 acc[4][4] = {};

    // staging: thread t -> row t>>3 (+i*32), 16B col t&7 pre-swizzled (rule #21)
    const int srow = t >> 3;                              // 0..31
    const int scolb = (((t & 7) ^ ((t >> 3) & 7)) << 4);  // swizzled src col byte
    const char* Zb = (const char*)Z;
    const size_t apan = ((size_t)(by * 128) << 10);

#define STG(kn, bpanv, db)                                                        \
    {                                                                             \
        const int kb_ = ((kn) << 7) + scolb;                                      \
        _Pragma("unroll") for (int i_ = 0; i_ < 4; ++i_) {                        \
            const size_t ro_ = ((size_t)(i_ * 32 + srow) << 10) + kb_;            \
            __builtin_amdgcn_global_load_lds(                                     \
                (const AS1 void*)(Zb + apan + ro_),                               \
                (AS3 void*)((char*)&lds[db][0][0] + i_ * 4096 + w * 1024),        \
                16, 0, 0);                                                        \
            __builtin_amdgcn_global_load_lds(                                     \
                (const AS1 void*)(Zb + (bpanv) + ro_),                            \
                (AS3 void*)((char*)&lds[db][1][0] + i_ * 4096 + w * 1024),        \
                16, 0, 0);                                                        \
        }                                                                         \
    }

    const float SC = 14.4269504088896340736f;  // log2(e)/tau
    const int g = lane >> 4;
    const int swz = (lane & 7) << 4;

    // prologue: first tile's K-iter 0
    STG(0, ((size_t)(bx0 * 128) << 10), 0);
    __syncthreads();

    for (int jt = 0; jt < NT; ++jt) {
        const int bx = bx0 + jt;
        const size_t bpan_n = ((size_t)((bx + 1) * 128) << 10);  // used only if jt+1<NT
#pragma unroll
        for (int k = 0; k < 8; ++k) {
            const int cur = k & 1;
            if (k < 7) {
                STG(k + 1, ((size_t)(bx * 128) << 10), cur ^ 1);
            } else if (jt + 1 < NT) {
                STG(0, bpan_n, cur ^ 1);
            }
            const char* Ab = (const char*)&lds[cur][0][0];
            const char* Bb = (const char*)&lds[cur][1][0];
#pragma unroll
            for (int kk = 0; kk < 2; ++kk) {
                const int koff = (((lane >> 4) << 4) + kk * 64) ^ swz;
                bf16x8 af[4], bfr[4];
#pragma unroll
                for (int mi = 0; mi < 4; ++mi) {
                    const int row = wr * 64 + mi * 16 + (lane & 15);
                    af[mi] = *(const bf16x8*)(Ab + row * 128 + koff);
                }
#pragma unroll
                for (int ni = 0; ni < 4; ++ni) {
                    const int row = wc * 64 + ni * 16 + (lane & 15);
                    bfr[ni] = *(const bf16x8*)(Bb + row * 128 + koff);
                }
#pragma unroll
                for (int mi = 0; mi < 4; ++mi)
#pragma unroll
                    for (int ni = 0; ni < 4; ++ni)
                        acc[mi][ni] = __builtin_amdgcn_mfma_f32_16x16x32_bf16(
                            af[mi], bfr[ni], acc[mi][ni], 0, 0, 0);
            }
            __syncthreads();  // drains vmcnt+lgkm: staged tile resident, reads done
        }

        // flush this tile: exp + row sums (by side) + col sums (bx side)
        const bool diag = (bx == by);
        float cs[4] = {0.f, 0.f, 0.f, 0.f};
#pragma unroll
        for (int mi = 0; mi < 4; ++mi) {
            float rs0 = 0.f, rs1 = 0.f, rs2 = 0.f, rs3 = 0.f;
#pragma unroll
            for (int ni = 0; ni < 4; ++ni) {
                f32x4 a = acc[mi][ni];
                const float e0 = exp2f(a[0] * SC);
                const float e1 = exp2f(a[1] * SC);
                const float e2 = exp2f(a[2] * SC);
                const float e3 = exp2f(a[3] * SC);
                rs0 += e0; rs1 += e1; rs2 += e2; rs3 += e3;
                cs[ni] += (e0 + e1) + (e2 + e3);
                acc[mi][ni][0] = 0.f; acc[mi][ni][1] = 0.f;  // re-zero for next tile
                acc[mi][ni][2] = 0.f; acc[mi][ni][3] = 0.f;
            }
#pragma unroll
            for (int m = 1; m < 16; m <<= 1) {
                rs0 += __shfl_xor(rs0, m, 64);
                rs1 += __shfl_xor(rs1, m, 64);
                rs2 += __shfl_xor(rs2, m, 64);
                rs3 += __shfl_xor(rs3, m, 64);
            }
            if ((lane & 15) == 0) {
                const int rbase = by * 128 + wr * 64 + mi * 16 + g * 4;
                atomicAdd(&rowsum[rbase + 0], rs0);
                atomicAdd(&rowsum[rbase + 1], rs1);
                atomicAdd(&rowsum[rbase + 2], rs2);
                atomicAdd(&rowsum[rbase + 3], rs3);
            }
        }
        if (!diag) {
#pragma unroll
            for (int ni = 0; ni < 4; ++ni) {
                float c = cs[ni];
                c += __shfl_xor(c, 16, 64);
                c += __shfl_xor(c, 32, 64);
                if (lane < 16)
                    atomicAdd(&rowsum[bx * 128 + wc * 64 + ni * 16 + lane], c);
            }
        }
    }
#undef STG

    // ---- last-block finalize (ticket) ----
    __threadfence();
    if (t == 0) lastsm = (atomicAdd(ticket, 1u) == (unsigned)(NBLK - 1)) ? 1u : 0u;
    __syncthreads();
    if (lastsm) {
        float l = 0.f;
        for (int r = t; r < BDIM; r += 256) {
            const float rs1 = atomicAdd(&rowsum[r], 0.f);          // coherent read
            const float rs2 = atomicAdd(&rowsum[r + BDIM], 0.f);
            const float p10 = pos10[r];
            const float pos = expf(p10);
            l += (logf(rs1 - pos) - p10) + (logf(rs2 - pos) - p10);
        }
#pragma unroll
        for (int m = 1; m < 64; m <<= 1) l += __shfl_xor(l, m, 64);
        if (lane == 0) redsm[w] = l;
        __syncthreads();
        if (t == 0)
            out[0] = (redsm[0] + redsm[1] + redsm[2] + redsm[3]) *
                     (1.0f / ((float)NROWS * (float)BDIM));
    }
}

extern "C" void kernel_launch(void* const* d_in, const int* in_sizes, int n_in,
                              void* d_out, int out_size, void* d_ws, size_t ws_size,
                              hipStream_t stream) {
    const float* z1 = (const float*)d_in[0];
    const float* z2 = (const float*)d_in[1];
    float* out = (float*)d_out;
    unsigned short* zb = (unsigned short*)d_ws;
    float* rowsum = (float*)((char*)d_ws + (size_t)NROWS * CDIM * 2);
    float* pos10 = rowsum + NROWS;
    unsigned* ticket = (unsigned*)(pos10 + BDIM);

    normalize_kernel<<<BDIM / 4, 256, 0, stream>>>(z1, z2, zb, pos10, rowsum, out, ticket);
    simgemm_kernel<<<NBLK, 256, 0, stream>>>(zb, rowsum, pos10, out, ticket);
}

// Round 9
// 139.040 us; speedup vs baseline: 1.6155x; 1.6155x over previous
//
#include <hip/hip_runtime.h>
#include <hip/hip_bf16.h>

// NT-Xent loss, MI355X. B=4096, C=512, N=8192, tau=0.1.
// ws layout: [0, 8MB)            bf16 normalized Z (ushort[8192*512])
//            [8MB, 8MB+32KB)     float rowsum[8192]
//            [8MB+32KB, +16KB)   float pos10[4096]  (pos_dot/tau, exact fp32)

#define BDIM 4096
#define CDIM 512
#define NROWS 8192
#define NTILE 32   // 8192 / 256
#define NKT 8      // K-tiles: 512 / 64
#define NBLK 576   // 512 full 256^2 tiles + 64 quarter (256x64) tiles

typedef __attribute__((ext_vector_type(4))) float f32x4;
typedef __attribute__((ext_vector_type(8))) short bf16x8;

#define AS1 __attribute__((address_space(1)))
#define AS3 __attribute__((address_space(3)))

__device__ __forceinline__ unsigned short f2bf_rne(float x) {
    unsigned u = __float_as_uint(x);
    u += 0x7fffu + ((u >> 16) & 1u);
    return (unsigned short)(u >> 16);
}

// ------- kernel 1: L2-normalize -> bf16, exact positive dot, zero rowsum/out -------
__global__ __launch_bounds__(256) void normalize_kernel(
    const float* __restrict__ z1, const float* __restrict__ z2,
    unsigned short* __restrict__ zb, float* __restrict__ pos10,
    float* __restrict__ rowsum, float* __restrict__ out) {
    if (blockIdx.x == 0) {  // fused zero-init (stream order -> visible to k2/k3)
#pragma unroll
        for (int i = 0; i < NROWS / 256; ++i) rowsum[i * 256 + threadIdx.x] = 0.f;
        if (threadIdx.x == 0) out[0] = 0.f;
    }
    const int w = threadIdx.x >> 6, lane = threadIdx.x & 63;
    const int r = blockIdx.x * 4 + w;  // pair index 0..4095
    const float4* p1 = (const float4*)(z1 + (size_t)r * CDIM);
    const float4* p2 = (const float4*)(z2 + (size_t)r * CDIM);
    float4 a0 = p1[lane], a1 = p1[64 + lane];
    float4 b0 = p2[lane], b1 = p2[64 + lane];
    float s1 = a0.x * a0.x + a0.y * a0.y + a0.z * a0.z + a0.w * a0.w +
               a1.x * a1.x + a1.y * a1.y + a1.z * a1.z + a1.w * a1.w;
    float s2 = b0.x * b0.x + b0.y * b0.y + b0.z * b0.z + b0.w * b0.w +
               b1.x * b1.x + b1.y * b1.y + b1.z * b1.z + b1.w * b1.w;
    float d = a0.x * b0.x + a0.y * b0.y + a0.z * b0.z + a0.w * b0.w +
              a1.x * b1.x + a1.y * b1.y + a1.z * b1.z + a1.w * b1.w;
#pragma unroll
    for (int m = 1; m < 64; m <<= 1) {
        s1 += __shfl_xor(s1, m, 64);
        s2 += __shfl_xor(s2, m, 64);
        d += __shfl_xor(d, m, 64);
    }
    const float n1 = fmaxf(sqrtf(s1), 1e-12f);
    const float n2 = fmaxf(sqrtf(s2), 1e-12f);
    const float i1 = 1.0f / n1, i2 = 1.0f / n2;
    ushort4 o;
    ushort4* q1 = (ushort4*)(zb + (size_t)r * CDIM);
    ushort4* q2 = (ushort4*)(zb + (size_t)(r + BDIM) * CDIM);
    o.x = f2bf_rne(a0.x * i1); o.y = f2bf_rne(a0.y * i1);
    o.z = f2bf_rne(a0.z * i1); o.w = f2bf_rne(a0.w * i1);
    q1[lane] = o;
    o.x = f2bf_rne(a1.x * i1); o.y = f2bf_rne(a1.y * i1);
    o.z = f2bf_rne(a1.z * i1); o.w = f2bf_rne(a1.w * i1);
    q1[64 + lane] = o;
    o.x = f2bf_rne(b0.x * i2); o.y = f2bf_rne(b0.y * i2);
    o.z = f2bf_rne(b0.z * i2); o.w = f2bf_rne(b0.w * i2);
    q2[lane] = o;
    o.x = f2bf_rne(b1.x * i2); o.y = f2bf_rne(b1.y * i2);
    o.z = f2bf_rne(b1.z * i2); o.w = f2bf_rne(b1.w * i2);
    q2[64 + lane] = o;
    if (lane == 0) pos10[r] = (d / (n1 * n2)) * 10.0f;
}

// ------- kernel 2: triangular fused exp(Z Z^T / tau) row+col sums -------
// Grid = 512 full 256^2 tiles (r7-proven 8-phase schedule, dispatched first,
// exactly 2 generations at 1 block/CU) + 64 quarter tiles (256x64, simple
// r4-proven dbuf loop) covering the 16 anti-diagonal (by+bx==31) tiles;
// quarters dispatch last and fill the gen-2 shadow (makespan ~2.25 gens vs
// r7's 3). XCD-chunked bijective remap over the 512 fulls (512 = 8*64).
__global__ __launch_bounds__(512, 2) void simgemm_kernel(
    const unsigned short* __restrict__ Z, float* __restrict__ rowsum) {
    __shared__ unsigned short lds[2][4][128 * 64];  // 128 KB

    const int t = threadIdx.x;
    const int lane = t & 63, w = t >> 6;  // 8 waves
    const int wr = w >> 2, wc = w & 3;    // 2 x 4
    const int srow = t >> 3;                              // 0..63
    const int scolb = (((t & 7) ^ ((t >> 3) & 7)) << 4);  // swizzled src col byte
    const char* Zb = (const char*)Z;
    const float SC = 14.4269504088896340736f;  // log2(e)/tau
    const int g = lane >> 4;
    const int arow = lane & 15;
    const int klo = (lane >> 4) << 4;
    const int swz = (lane & 7) << 4;
    const int bid = blockIdx.x;

    if (bid < 512) {
        // ---------------- FULL 256x256 tile, r7 8-phase schedule ----------------
        const int fid = (bid & 7) * 64 + (bid >> 3);  // XCD-chunked remap
        // decode fid -> (by,bx) over tri tiles, skipping anti-diagonal by+bx==31
        int by = 0, rem = fid;
        while (true) {
            const int cnt = (NTILE - by) - (by <= 15 ? 1 : 0);
            if (rem < cnt) break;
            rem -= cnt; ++by;
        }
        int bx = by + rem;
        if (by <= 15 && bx >= 31 - by) ++bx;  // skip the overhang tile
        const bool diag = (bx == by);

        f32x4 acc[8][4] = {};
        const size_t apan = ((size_t)(by * 256) << 10);
        const size_t bpan = ((size_t)(bx * 256) << 10);

#define STG(T, J)                                                                \
    {                                                                            \
        const size_t pb_ = ((J) < 2 ? apan : bpan);                              \
        const char* g0_ = Zb + pb_ +                                             \
            ((size_t)((((J) & 1) * 128) + srow) << 10) + ((T) * 128) + scolb;    \
        char* d0_ = (char*)&lds[(T) & 1][J][0] + w * 1024;                       \
        __builtin_amdgcn_global_load_lds((const AS1 void*)g0_,                   \
                                         (AS3 void*)d0_, 16, 0, 0);              \
        __builtin_amdgcn_global_load_lds((const AS1 void*)(g0_ + (64 << 10)),    \
                                         (AS3 void*)(d0_ + 8192), 16, 0, 0);     \
    }

        // prologue: tile0 fully + tile1's B0,A0
        STG(0, 2); STG(0, 3); STG(0, 0); STG(0, 1); STG(1, 2); STG(1, 0);
        asm volatile("s_waitcnt vmcnt(4)\n\ts_barrier" ::: "memory");

        const int brow0 = (wc & 1) * 64;
#pragma unroll
        for (int T = 0; T < NKT; ++T) {
            const int buf = T & 1;
            const char* Ab = (const char*)&lds[buf][wr][0];
            const char* Bb = (const char*)&lds[buf][2 + (wc >> 1)][0];
            if (T >= 1) {
                if (T < NKT - 1)
                    asm volatile("s_waitcnt vmcnt(4)\n\ts_barrier" ::: "memory");
                else
                    asm volatile("s_waitcnt vmcnt(0)\n\ts_barrier" ::: "memory");
            }

            bf16x8 af[4][2], bf[4][2];

            // q0: read A mi0-3 + B ni0-1; stage (T+1).B1; MFMA (0-3, 0-1)
#pragma unroll
            for (int mi = 0; mi < 4; ++mi)
#pragma unroll
                for (int kk = 0; kk < 2; ++kk)
                    af[mi][kk] = *(const bf16x8*)(Ab + (mi * 16 + arow) * 128 +
                                                  ((kk * 64 + klo) ^ swz));
#pragma unroll
            for (int ni = 0; ni < 2; ++ni)
#pragma unroll
                for (int kk = 0; kk < 2; ++kk)
                    bf[ni][kk] = *(const bf16x8*)(Bb + (brow0 + ni * 16 + arow) * 128 +
                                                  ((kk * 64 + klo) ^ swz));
            if (T + 1 < NKT) STG(T + 1, 3);
            asm volatile("s_barrier" ::: "memory");
            __builtin_amdgcn_s_setprio(1);
#pragma unroll
            for (int mi = 0; mi < 4; ++mi)
#pragma unroll
                for (int ni = 0; ni < 2; ++ni)
#pragma unroll
                    for (int kk = 0; kk < 2; ++kk)
                        acc[mi][ni] = __builtin_amdgcn_mfma_f32_16x16x32_bf16(
                            af[mi][kk], bf[ni][kk], acc[mi][ni], 0, 0, 0);
            __builtin_amdgcn_s_setprio(0);
            asm volatile("s_waitcnt lgkmcnt(0)\n\ts_barrier" ::: "memory");

            // q1: read B ni2-3; stage (T+1).A1; MFMA (0-3, 2-3)
#pragma unroll
            for (int ni = 2; ni < 4; ++ni)
#pragma unroll
                for (int kk = 0; kk < 2; ++kk)
                    bf[ni][kk] = *(const bf16x8*)(Bb + (brow0 + ni * 16 + arow) * 128 +
                                                  ((kk * 64 + klo) ^ swz));
            if (T + 1 < NKT) STG(T + 1, 1);
            asm volatile("s_barrier" ::: "memory");
            __builtin_amdgcn_s_setprio(1);
#pragma unroll
            for (int mi = 0; mi < 4; ++mi)
#pragma unroll
                for (int ni = 2; ni < 4; ++ni)
#pragma unroll
                    for (int kk = 0; kk < 2; ++kk)
                        acc[mi][ni] = __builtin_amdgcn_mfma_f32_16x16x32_bf16(
                            af[mi][kk], bf[ni][kk], acc[mi][ni], 0, 0, 0);
            __builtin_amdgcn_s_setprio(0);
            asm volatile("s_waitcnt lgkmcnt(0)\n\ts_barrier" ::: "memory");

            // q2: read A mi4-7; stage (T+2).B0; MFMA (4-7, 0-1)
#pragma unroll
            for (int mi = 0; mi < 4; ++mi)
#pragma unroll
                for (int kk = 0; kk < 2; ++kk)
                    af[mi][kk] = *(const bf16x8*)(Ab + ((mi + 4) * 16 + arow) * 128 +
                                                  ((kk * 64 + klo) ^ swz));
            if (T + 2 < NKT) STG(T + 2, 2);
            asm volatile("s_barrier" ::: "memory");
            __builtin_amdgcn_s_setprio(1);
#pragma unroll
            for (int mi = 0; mi < 4; ++mi)
#pragma unroll
                for (int ni = 0; ni < 2; ++ni)
#pragma unroll
                    for (int kk = 0; kk < 2; ++kk)
                        acc[mi + 4][ni] = __builtin_amdgcn_mfma_f32_16x16x32_bf16(
                            af[mi][kk], bf[ni][kk], acc[mi + 4][ni], 0, 0, 0);
            __builtin_amdgcn_s_setprio(0);
            asm volatile("s_waitcnt lgkmcnt(0)\n\ts_barrier" ::: "memory");

            // q3: no reads; stage (T+2).A0; MFMA (4-7, 2-3)
            if (T + 2 < NKT) STG(T + 2, 0);
            asm volatile("s_barrier" ::: "memory");
            __builtin_amdgcn_s_setprio(1);
#pragma unroll
            for (int mi = 0; mi < 4; ++mi)
#pragma unroll
                for (int ni = 2; ni < 4; ++ni)
#pragma unroll
                    for (int kk = 0; kk < 2; ++kk)
                        acc[mi + 4][ni] = __builtin_amdgcn_mfma_f32_16x16x32_bf16(
                            af[mi][kk], bf[ni][kk], acc[mi + 4][ni], 0, 0, 0);
            __builtin_amdgcn_s_setprio(0);
            asm volatile("s_waitcnt lgkmcnt(0)\n\ts_barrier" ::: "memory");
        }
#undef STG

        // epilogue. C/D: row = wr*128+mi*16+(lane>>4)*4+j, col = wc*64+ni*16+(lane&15)
        float cs[4] = {0.f, 0.f, 0.f, 0.f};
#pragma unroll
        for (int mi = 0; mi < 8; ++mi) {
            float rs0 = 0.f, rs1 = 0.f, rs2 = 0.f, rs3 = 0.f;
#pragma unroll
            for (int ni = 0; ni < 4; ++ni) {
                f32x4 a = acc[mi][ni];
                const float e0 = exp2f(a[0] * SC);
                const float e1 = exp2f(a[1] * SC);
                const float e2 = exp2f(a[2] * SC);
                const float e3 = exp2f(a[3] * SC);
                rs0 += e0; rs1 += e1; rs2 += e2; rs3 += e3;
                cs[ni] += (e0 + e1) + (e2 + e3);
            }
#pragma unroll
            for (int m = 1; m < 16; m <<= 1) {
                rs0 += __shfl_xor(rs0, m, 64);
                rs1 += __shfl_xor(rs1, m, 64);
                rs2 += __shfl_xor(rs2, m, 64);
                rs3 += __shfl_xor(rs3, m, 64);
            }
            if ((lane & 15) == 0) {
                const int rbase = by * 256 + wr * 128 + mi * 16 + g * 4;
                atomicAdd(&rowsum[rbase + 0], rs0);
                atomicAdd(&rowsum[rbase + 1], rs1);
                atomicAdd(&rowsum[rbase + 2], rs2);
                atomicAdd(&rowsum[rbase + 3], rs3);
            }
        }
        if (!diag) {
#pragma unroll
            for (int ni = 0; ni < 4; ++ni) {
                float c = cs[ni];
                c += __shfl_xor(c, 16, 64);
                c += __shfl_xor(c, 32, 64);
                if (lane < 16)
                    atomicAdd(&rowsum[bx * 256 + wc * 64 + ni * 16 + lane], c);
            }
        }
    } else {
        // ---------------- QUARTER 256x64 tile (anti-diagonal overhang) ----------------
        const int qi = bid - 512;
        const int by = qi >> 2, bx = 31 - (qi >> 2), cq = qi & 3;  // off-diag always
        const size_t apan = ((size_t)(by * 256) << 10);
        const size_t bq = ((size_t)(bx * 256 + cq * 64) << 10);

        f32x4 accq[8] = {};

#define GLD(gp, dp) __builtin_amdgcn_global_load_lds((const AS1 void*)(gp), (AS3 void*)(dp), 16, 0, 0)
#define STGQ(T, d)                                                               \
    {                                                                            \
        _Pragma("unroll") for (int J_ = 0; J_ < 2; ++J_) {                       \
            const char* g0_ = Zb + apan +                                        \
                ((size_t)(J_ * 128 + srow) << 10) + ((T) << 7) + scolb;          \
            char* d0_ = (char*)&lds[d][J_][0] + w * 1024;                        \
            GLD(g0_, d0_);                                                       \
            GLD(g0_ + (64 << 10), d0_ + 8192);                                   \
        }                                                                        \
        GLD(Zb + bq + ((size_t)srow << 10) + ((T) << 7) + scolb,                 \
            (char*)&lds[d][2][0] + w * 1024);                                    \
    }

        STGQ(0, 0);
        __syncthreads();  // compiler drains vmcnt
#pragma unroll
        for (int T = 0; T < NKT; ++T) {
            const int d = T & 1;
            if (T < NKT - 1) STGQ(T + 1, d ^ 1);
            const char* Aw = (const char*)&lds[d][wr][0];
            const char* Bq = (const char*)&lds[d][2][0];
#pragma unroll
            for (int kk = 0; kk < 2; ++kk) {
                const int koff = (kk * 64 + klo) ^ swz;
                bf16x8 bfq = *(const bf16x8*)(Bq + (wc * 16 + arow) * 128 + koff);
#pragma unroll
                for (int mi = 0; mi < 8; ++mi) {
                    bf16x8 afm = *(const bf16x8*)(Aw + (mi * 16 + arow) * 128 + koff);
                    accq[mi] = __builtin_amdgcn_mfma_f32_16x16x32_bf16(
                        afm, bfq, accq[mi], 0, 0, 0);
                }
            }
            __syncthreads();  // drains vmcnt+lgkm
        }
#undef STGQ
#undef GLD

        // epilogue: rows by*256+wr*128+mi*16+g*4+j; cols bx*256+cq*64+wc*16+(lane&15)
        float cs = 0.f;
#pragma unroll
        for (int mi = 0; mi < 8; ++mi) {
            f32x4 a = accq[mi];
            const float e0 = exp2f(a[0] * SC);
            const float e1 = exp2f(a[1] * SC);
            const float e2 = exp2f(a[2] * SC);
            const float e3 = exp2f(a[3] * SC);
            float rs0 = e0, rs1 = e1, rs2 = e2, rs3 = e3;
            cs += (e0 + e1) + (e2 + e3);
#pragma unroll
            for (int m = 1; m < 16; m <<= 1) {
                rs0 += __shfl_xor(rs0, m, 64);
                rs1 += __shfl_xor(rs1, m, 64);
                rs2 += __shfl_xor(rs2, m, 64);
                rs3 += __shfl_xor(rs3, m, 64);
            }
            if ((lane & 15) == 0) {
                const int rbase = by * 256 + wr * 128 + mi * 16 + g * 4;
                atomicAdd(&rowsum[rbase + 0], rs0);
                atomicAdd(&rowsum[rbase + 1], rs1);
                atomicAdd(&rowsum[rbase + 2], rs2);
                atomicAdd(&rowsum[rbase + 3], rs3);
            }
        }
        cs += __shfl_xor(cs, 16, 64);
        cs += __shfl_xor(cs, 32, 64);
        if (lane < 16)
            atomicAdd(&rowsum[bx * 256 + cq * 64 + wc * 16 + lane], cs);
    }
}

// ------- kernel 3: per-pair loss from rowsum + pos10, reduce to scalar -------
__global__ __launch_bounds__(256) void finalize_kernel(
    const float* __restrict__ rowsum, const float* __restrict__ pos10,
    float* __restrict__ out) {
    __shared__ float sm[4];
    const int w = threadIdx.x >> 6, lane = threadIdx.x & 63;
    const int r = blockIdx.x * 256 + threadIdx.x;  // 0..4095
    const float p10 = pos10[r];
    const float pos = expf(p10);
    float l = (logf(rowsum[r] - pos) - p10) +
              (logf(rowsum[r + BDIM] - pos) - p10);
#pragma unroll
    for (int m = 1; m < 64; m <<= 1) l += __shfl_xor(l, m, 64);
    if (lane == 0) sm[w] = l;
    __syncthreads();
    if (threadIdx.x == 0) {
        const float tot = sm[0] + sm[1] + sm[2] + sm[3];
        atomicAdd(out, tot * (1.0f / ((float)NROWS * (float)BDIM)));
    }
}

extern "C" void kernel_launch(void* const* d_in, const int* in_sizes, int n_in,
                              void* d_out, int out_size, void* d_ws, size_t ws_size,
                              hipStream_t stream) {
    const float* z1 = (const float*)d_in[0];
    const float* z2 = (const float*)d_in[1];
    float* out = (float*)d_out;
    unsigned short* zb = (unsigned short*)d_ws;
    float* rowsum = (float*)((char*)d_ws + (size_t)NROWS * CDIM * 2);
    float* pos10 = rowsum + NROWS;

    normalize_kernel<<<BDIM / 4, 256, 0, stream>>>(z1, z2, zb, pos10, rowsum, out);
    simgemm_kernel<<<NBLK, 512, 0, stream>>>(zb, rowsum);
    finalize_kernel<<<BDIM / 256, 256, 0, stream>>>(rowsum, pos10, out);
}